// Round 3
// baseline (668.918 us; speedup 1.0000x reference)
//
#include <hip/hip_runtime.h>

// GCN 3-layer: N=100000 nodes, E=1600000 edges, dims 20->64->48->32.
// CSR-by-dst (src only; norm recomputed from dinv in aggregate), per layer:
// skinny GEMM (fused BN+ReLU of prev layer) -> wave-gather aggregate with
// fused BN-stats (bucketed atomics) -> finalize. Final BN applied into d_out.

#define NN 100000
#define NE 1600000
constexpr float BN_EPS_F = 1e-5f;

// ---------------- CSR build ----------------

__global__ void count_deg(const int* __restrict__ dst, int* __restrict__ deg, int e) {
  int i0 = (blockIdx.x * blockDim.x + threadIdx.x) * 4;
  if (i0 >= e) return;  // e % 4 == 0
  int4 d = *(const int4*)(dst + i0);
  atomicAdd(&deg[d.x], 1);
  atomicAdd(&deg[d.y], 1);
  atomicAdd(&deg[d.z], 1);
  atomicAdd(&deg[d.w], 1);
}

__global__ void scan_block_sums(const int* __restrict__ deg, int* __restrict__ bsums, int n) {
  __shared__ int sd[256];
  int tid = threadIdx.x;
  int base = blockIdx.x * 1024;
  int s = 0;
#pragma unroll
  for (int j = 0; j < 4; j++) {
    int idx = base + tid * 4 + j;
    if (idx < n) s += deg[idx];
  }
  sd[tid] = s;
  __syncthreads();
  for (int o = 128; o > 0; o >>= 1) {
    if (tid < o) sd[tid] += sd[tid + o];
    __syncthreads();
  }
  if (tid == 0) bsums[blockIdx.x] = sd[0];
}

__global__ void scan_bsums(int* __restrict__ bsums, int nb, int* __restrict__ rowptr, int n) {
  __shared__ int sd[128];
  int tid = threadIdx.x;
  int v = (tid < nb) ? bsums[tid] : 0;
  sd[tid] = v;
  __syncthreads();
  for (int o = 1; o < 128; o <<= 1) {
    int t = (tid >= o) ? sd[tid - o] : 0;
    __syncthreads();
    sd[tid] += t;
    __syncthreads();
  }
  if (tid < nb) bsums[tid] = sd[tid] - v;  // exclusive
  if (tid == nb - 1) rowptr[n] = sd[tid];  // grand total
}

// also computes dinv = rsqrt(deg+1) (self loop) — fused to save a pass
__global__ void scan_write_rowptr(const int* __restrict__ deg, const int* __restrict__ bsums,
                                  int* __restrict__ rowptr, int* __restrict__ cursor,
                                  float* __restrict__ dinv, int n) {
  __shared__ int sd[256];
  int tid = threadIdx.x;
  int base = blockIdx.x * 1024;
  int c[4];
  int s = 0;
#pragma unroll
  for (int j = 0; j < 4; j++) {
    int idx = base + tid * 4 + j;
    c[j] = (idx < n) ? deg[idx] : 0;
    s += c[j];
  }
  sd[tid] = s;
  __syncthreads();
  for (int o = 1; o < 256; o <<= 1) {
    int t = (tid >= o) ? sd[tid - o] : 0;
    __syncthreads();
    sd[tid] += t;
    __syncthreads();
  }
  int off = bsums[blockIdx.x] + sd[tid] - s;
#pragma unroll
  for (int j = 0; j < 4; j++) {
    int idx = base + tid * 4 + j;
    if (idx < n) {
      rowptr[idx] = off;
      cursor[idx] = off;
      dinv[idx] = rsqrtf((float)(c[j] + 1));
      off += c[j];
    }
  }
}

// one 4B scatter store per edge (norm recomputed later from dinv)
__global__ void fill_csr(const int* __restrict__ src, const int* __restrict__ dst,
                         int* __restrict__ cursor, int* __restrict__ csr_src, int e) {
  int i0 = (blockIdx.x * blockDim.x + threadIdx.x) * 4;
  if (i0 >= e) return;  // e % 4 == 0
  int4 s = *(const int4*)(src + i0);
  int4 d = *(const int4*)(dst + i0);
  int p0 = atomicAdd(&cursor[d.x], 1);
  int p1 = atomicAdd(&cursor[d.y], 1);
  int p2 = atomicAdd(&cursor[d.z], 1);
  int p3 = atomicAdd(&cursor[d.w], 1);
  csr_src[p0] = s.x;
  csr_src[p1] = s.y;
  csr_src[p2] = s.z;
  csr_src[p3] = s.w;
}

// ---------------- dense skinny GEMM with fused BN-affine+ReLU on input ----------------

template <int K, int C, int R>
__global__ void gemm_affine(const float* __restrict__ h, const float* __restrict__ W,
                            const float* __restrict__ scale, const float* __restrict__ shift,
                            float* __restrict__ out, int n) {
  __shared__ float Wl[K * C];
  __shared__ float Hl[R][K];
  int tid = threadIdx.x;
  for (int i = tid; i < K * C; i += 256) Wl[i] = W[i];
  int row0 = blockIdx.x * R;
  for (int i = tid; i < R * K; i += 256) {
    int r = i / K, k = i % K;
    int row = row0 + r;
    float v = 0.f;
    if (row < n) v = h[row * K + k];
    if (scale) {
      v = v * scale[k] + shift[k];
      v = fmaxf(v, 0.f);
    }
    Hl[r][k] = v;
  }
  __syncthreads();
  int r = tid / C, c = tid % C;
  if (r < R) {
    int row = row0 + r;
    if (row < n) {
      float acc = 0.f;
#pragma unroll
      for (int k = 0; k < K; k++) acc = fmaf(Hl[r][k], Wl[k * C + c], acc);
      out[row * C + c] = acc;
    }
  }
}

// ---------------- aggregation + fused BN stats ----------------
// LW-lane sub-wave per node, lane = feature. Edge loop unrolled 16/4/1 with
// int4 index loads; norm factored: out = dd*(sum dinv[s]*m[s] + dd*m[d]) + b.
// Requires n % (256/LW) == 0 (100000 % 4 == 0, % 8 == 0).

template <int C, int LW>
__launch_bounds__(256)
__global__ void aggregate(const float* __restrict__ m, const int* __restrict__ rowptr,
                          const int* __restrict__ csr_src, const float* __restrict__ dinv,
                          const float* __restrict__ bias, float* __restrict__ out,
                          float* __restrict__ gsum, int n) {
  constexpr int NPB = 256 / LW;
  __shared__ float ssum[256], ssq[256];
  int tid = threadIdx.x;
  int sub = tid / LW;
  int lane = tid % LW;
  int cl = (lane < C) ? lane : lane - C;  // branchless in-bounds channel
  int d = blockIdx.x * NPB + sub;
  int start = rowptr[d], end = rowptr[d + 1];
  float dd = dinv[d];
  float acc = dd * m[d * C + cl];  // self loop (gets *dd at the end)
  int j = start;
  int aligned = (start + 3) & ~3;
  int pe = aligned < end ? aligned : end;
  for (; j < pe; j++) {
    int s = csr_src[j];
    acc += dinv[s] * m[s * C + cl];
  }
  for (; j + 16 <= end; j += 16) {
    int4 s0 = *(const int4*)(csr_src + j);
    int4 s1 = *(const int4*)(csr_src + j + 4);
    int4 s2 = *(const int4*)(csr_src + j + 8);
    int4 s3 = *(const int4*)(csr_src + j + 12);
    float w0 = dinv[s0.x], w1 = dinv[s0.y], w2 = dinv[s0.z], w3 = dinv[s0.w];
    float w4 = dinv[s1.x], w5 = dinv[s1.y], w6 = dinv[s1.z], w7 = dinv[s1.w];
    float w8 = dinv[s2.x], w9 = dinv[s2.y], wa = dinv[s2.z], wb = dinv[s2.w];
    float wc = dinv[s3.x], wd = dinv[s3.y], we = dinv[s3.z], wf = dinv[s3.w];
    float v0 = m[s0.x * C + cl], v1 = m[s0.y * C + cl];
    float v2 = m[s0.z * C + cl], v3 = m[s0.w * C + cl];
    float v4 = m[s1.x * C + cl], v5 = m[s1.y * C + cl];
    float v6 = m[s1.z * C + cl], v7 = m[s1.w * C + cl];
    float v8 = m[s2.x * C + cl], v9 = m[s2.y * C + cl];
    float va = m[s2.z * C + cl], vb = m[s2.w * C + cl];
    float vc = m[s3.x * C + cl], vd = m[s3.y * C + cl];
    float ve = m[s3.z * C + cl], vf = m[s3.w * C + cl];
    acc += w0 * v0 + w1 * v1 + w2 * v2 + w3 * v3;
    acc += w4 * v4 + w5 * v5 + w6 * v6 + w7 * v7;
    acc += w8 * v8 + w9 * v9 + wa * va + wb * vb;
    acc += wc * vc + wd * vd + we * ve + wf * vf;
  }
  for (; j + 4 <= end; j += 4) {
    int4 s0 = *(const int4*)(csr_src + j);
    float w0 = dinv[s0.x], w1 = dinv[s0.y], w2 = dinv[s0.z], w3 = dinv[s0.w];
    float v0 = m[s0.x * C + cl], v1 = m[s0.y * C + cl];
    float v2 = m[s0.z * C + cl], v3 = m[s0.w * C + cl];
    acc += w0 * v0 + w1 * v1 + w2 * v2 + w3 * v3;
  }
  for (; j < end; j++) {
    int s = csr_src[j];
    acc += dinv[s] * m[s * C + cl];
  }
  float val = dd * acc;
  float s = 0.f, q = 0.f;
  if (lane < C) {
    val += bias[lane];
    out[d * C + lane] = val;
    s = val;
    q = val * val;
  }
  ssum[tid] = s;
  ssq[tid] = q;
  __syncthreads();
  if (tid < C) {
    float ts = 0.f, tq = 0.f;
#pragma unroll
    for (int k = 0; k < NPB; k++) {
      ts += ssum[k * LW + tid];
      tq += ssq[k * LW + tid];
    }
    int bucket = blockIdx.x & 31;
    atomicAdd(&gsum[bucket * 128 + tid], ts);
    atomicAdd(&gsum[bucket * 128 + 64 + tid], tq);
  }
}

// ---------------- BN finalize / apply ----------------

__global__ void bn_finalize(const float* __restrict__ gsum, const float* __restrict__ g,
                            const float* __restrict__ beta, float* __restrict__ scale,
                            float* __restrict__ shift, int C, float invn) {
  int i = threadIdx.x;
  if (i < C) {
    float s = 0.f, q = 0.f;
    for (int b = 0; b < 32; b++) {
      s += gsum[b * 128 + i];
      q += gsum[b * 128 + 64 + i];
    }
    float mean = s * invn;
    float var = q * invn - mean * mean;
    var = fmaxf(var, 0.f);
    float inv = rsqrtf(var + BN_EPS_F);
    float sc = g[i] * inv;
    scale[i] = sc;
    shift[i] = beta[i] - mean * sc;
  }
}

__global__ void bn_apply_out(const float* __restrict__ h, const float* __restrict__ scale,
                             const float* __restrict__ shift, float* __restrict__ out, int total) {
  int i = blockIdx.x * blockDim.x + threadIdx.x;
  if (i < total) {
    int c = i & 31;
    out[i] = h[i] * scale[c] + shift[c];
  }
}

// ---------------- launch ----------------

extern "C" void kernel_launch(void* const* d_in, const int* in_sizes, int n_in,
                              void* d_out, int out_size, void* d_ws, size_t ws_size,
                              hipStream_t stream) {
  const float* x = (const float*)d_in[0];
  const int* ei = (const int*)d_in[1];
  const float* W1 = (const float*)d_in[2];
  const float* b1 = (const float*)d_in[3];
  const float* g1 = (const float*)d_in[4];
  const float* be1 = (const float*)d_in[5];
  const float* W2 = (const float*)d_in[6];
  const float* b2 = (const float*)d_in[7];
  const float* g2 = (const float*)d_in[8];
  const float* be2 = (const float*)d_in[9];
  const float* W3 = (const float*)d_in[10];
  const float* b3 = (const float*)d_in[11];
  const float* g3 = (const float*)d_in[12];
  const float* be3 = (const float*)d_in[13];
  float* out = (float*)d_out;

  const int* src = ei;
  const int* dst = ei + NE;

  char* ws = (char*)d_ws;
  size_t off = 0;
  auto alloc = [&](size_t bytes) -> void* {
    void* p = ws + off;
    off += bytes;
    off = (off + 255) & ~(size_t)255;
    return p;
  };
  int* deg = (int*)alloc(NN * 4);
  int* rowptr = (int*)alloc((NN + 1) * 4);
  int* cursor = (int*)alloc(NN * 4);
  int* bsums = (int*)alloc(128 * 4);
  int* csr_src = (int*)alloc(NE * 4);
  float* dinv = (float*)alloc(NN * 4);
  float* gsum = (float*)alloc(3 * 32 * 128 * 4);  // per layer: 32 buckets x [sum64|sq64]
  float* scsh = (float*)alloc(3 * 128 * 4);       // per layer: [scale64|shift64]
  float* bufA = (float*)alloc((size_t)NN * 64 * 4);
  float* bufB = (float*)alloc((size_t)NN * 64 * 4);

  hipMemsetAsync(deg, 0, NN * 4, stream);
  hipMemsetAsync(gsum, 0, 3 * 32 * 128 * 4, stream);

  const int nb = (NN + 1023) / 1024;  // 98
  count_deg<<<(NE / 4 + 255) / 256, 256, 0, stream>>>(dst, deg, NE);
  scan_block_sums<<<nb, 256, 0, stream>>>(deg, bsums, NN);
  scan_bsums<<<1, 128, 0, stream>>>(bsums, nb, rowptr, NN);
  scan_write_rowptr<<<nb, 256, 0, stream>>>(deg, bsums, rowptr, cursor, dinv, NN);
  fill_csr<<<(NE / 4 + 255) / 256, 256, 0, stream>>>(src, dst, cursor, csr_src, NE);

  const float invn = 1.f / (float)NN;

  // layer 1: x[.,20] @ W1 -> 64
  gemm_affine<20, 64, 4><<<(NN + 3) / 4, 256, 0, stream>>>(x, W1, nullptr, nullptr, bufA, NN);
  aggregate<64, 64><<<NN / 4, 256, 0, stream>>>(bufA, rowptr, csr_src, dinv, b1, bufB, gsum, NN);
  bn_finalize<<<1, 64, 0, stream>>>(gsum, g1, be1, scsh + 0, scsh + 64, 64, invn);

  // layer 2: relu(bn(h)) @ W2 -> 48
  gemm_affine<64, 48, 5><<<(NN + 4) / 5, 256, 0, stream>>>(bufB, W2, scsh + 0, scsh + 64, bufA, NN);
  aggregate<48, 64><<<NN / 4, 256, 0, stream>>>(bufA, rowptr, csr_src, dinv, b2, bufB, gsum + 4096, NN);
  bn_finalize<<<1, 64, 0, stream>>>(gsum + 4096, g2, be2, scsh + 128, scsh + 192, 48, invn);

  // layer 3: relu(bn(h)) @ W3 -> 32
  gemm_affine<48, 32, 8><<<(NN + 7) / 8, 256, 0, stream>>>(bufB, W3, scsh + 128, scsh + 192, bufA, NN);
  aggregate<32, 32><<<NN / 8, 256, 0, stream>>>(bufA, rowptr, csr_src, dinv, b3, bufB, gsum + 8192, NN);
  bn_finalize<<<1, 64, 0, stream>>>(gsum + 8192, g3, be3, scsh + 256, scsh + 320, 32, invn);

  bn_apply_out<<<(NN * 32 + 255) / 256, 256, 0, stream>>>(bufB, scsh + 256, scsh + 320, out, NN * 32);
}

// Round 4
// 607.133 us; speedup vs baseline: 1.1018x; 1.1018x over previous
//
#include <hip/hip_runtime.h>

// GCN 3-layer: N=100000 nodes, E=1600000 edges, dims 20->64->48->32.
// CSR-by-dst (src only; norm recomputed from dinv in aggregate), per layer:
// skinny GEMM (fused BN+ReLU of prev layer) -> wave-gather aggregate with
// fused BN-stats (bucketed atomics) -> finalize. Final BN applied into d_out.
// fill_csr is XCD-range-partitioned: each block handles one 1/8 dst-range so
// scattered stores stay in one XCD's L2 slice (blockIdx%8 locality heuristic).

#define NN 100000
#define NE 1600000
constexpr float BN_EPS_F = 1e-5f;
#define NRANGE 8
#define RANGE_SZ ((NN + NRANGE - 1) / NRANGE)  // 12500

// ---------------- CSR build ----------------

__global__ void count_deg(const int* __restrict__ dst, int* __restrict__ deg, int e) {
  int i = blockIdx.x * blockDim.x + threadIdx.x;
  if (i < e) atomicAdd(&deg[dst[i]], 1);
}

__global__ void scan_block_sums(const int* __restrict__ deg, int* __restrict__ bsums, int n) {
  __shared__ int sd[256];
  int tid = threadIdx.x;
  int base = blockIdx.x * 1024;
  int s = 0;
#pragma unroll
  for (int j = 0; j < 4; j++) {
    int idx = base + tid * 4 + j;
    if (idx < n) s += deg[idx];
  }
  sd[tid] = s;
  __syncthreads();
  for (int o = 128; o > 0; o >>= 1) {
    if (tid < o) sd[tid] += sd[tid + o];
    __syncthreads();
  }
  if (tid == 0) bsums[blockIdx.x] = sd[0];
}

__global__ void scan_bsums(int* __restrict__ bsums, int nb, int* __restrict__ rowptr, int n) {
  __shared__ int sd[128];
  int tid = threadIdx.x;
  int v = (tid < nb) ? bsums[tid] : 0;
  sd[tid] = v;
  __syncthreads();
  for (int o = 1; o < 128; o <<= 1) {
    int t = (tid >= o) ? sd[tid - o] : 0;
    __syncthreads();
    sd[tid] += t;
    __syncthreads();
  }
  if (tid < nb) bsums[tid] = sd[tid] - v;  // exclusive
  if (tid == nb - 1) rowptr[n] = sd[tid];  // grand total
}

// also computes dinv = rsqrt(deg+1) (self loop) — fused to save a pass
__global__ void scan_write_rowptr(const int* __restrict__ deg, const int* __restrict__ bsums,
                                  int* __restrict__ rowptr, int* __restrict__ cursor,
                                  float* __restrict__ dinv, int n) {
  __shared__ int sd[256];
  int tid = threadIdx.x;
  int base = blockIdx.x * 1024;
  int c[4];
  int s = 0;
#pragma unroll
  for (int j = 0; j < 4; j++) {
    int idx = base + tid * 4 + j;
    c[j] = (idx < n) ? deg[idx] : 0;
    s += c[j];
  }
  sd[tid] = s;
  __syncthreads();
  for (int o = 1; o < 256; o <<= 1) {
    int t = (tid >= o) ? sd[tid - o] : 0;
    __syncthreads();
    sd[tid] += t;
    __syncthreads();
  }
  int off = bsums[blockIdx.x] + sd[tid] - s;
#pragma unroll
  for (int j = 0; j < 4; j++) {
    int idx = base + tid * 4 + j;
    if (idx < n) {
      rowptr[idx] = off;
      cursor[idx] = off;
      dinv[idx] = rsqrtf((float)(c[j] + 1));
      off += c[j];
    }
  }
}

// XCD-range-partitioned scatter: block handles dst-range blockIdx%8 only.
// Each range's cursor slice (~50KB) + csr slice (~0.8MB) stays hot in one
// XCD's L2, so 4B scattered stores fully populate lines before writeback.
// Edge list is re-read 8x but is L3-resident (12.8MB << 256MB).
__global__ void fill_csr_ranged(const int* __restrict__ src, const int* __restrict__ dst,
                                int* __restrict__ cursor, int* __restrict__ csr_src, int e) {
  int rng = blockIdx.x & (NRANGE - 1);  // XCD-locality heuristic only; correctness-independent
  int gb = blockIdx.x >> 3;
  int lo = rng * RANGE_SZ;
  int hi = lo + RANGE_SZ;
  int i0 = (gb * 256 + threadIdx.x) * 4;
  if (i0 >= e) return;  // e % 4 == 0
  int4 s = *(const int4*)(src + i0);
  int4 d = *(const int4*)(dst + i0);
  if (d.x >= lo && d.x < hi) { int p = atomicAdd(&cursor[d.x], 1); csr_src[p] = s.x; }
  if (d.y >= lo && d.y < hi) { int p = atomicAdd(&cursor[d.y], 1); csr_src[p] = s.y; }
  if (d.z >= lo && d.z < hi) { int p = atomicAdd(&cursor[d.z], 1); csr_src[p] = s.z; }
  if (d.w >= lo && d.w < hi) { int p = atomicAdd(&cursor[d.w], 1); csr_src[p] = s.w; }
}

// ---------------- dense skinny GEMM with fused BN-affine+ReLU on input ----------------

template <int K, int C, int R>
__global__ void gemm_affine(const float* __restrict__ h, const float* __restrict__ W,
                            const float* __restrict__ scale, const float* __restrict__ shift,
                            float* __restrict__ out, int n) {
  __shared__ float Wl[K * C];
  __shared__ float Hl[R][K];
  int tid = threadIdx.x;
  for (int i = tid; i < K * C; i += 256) Wl[i] = W[i];
  int row0 = blockIdx.x * R;
  for (int i = tid; i < R * K; i += 256) {
    int r = i / K, k = i % K;
    int row = row0 + r;
    float v = 0.f;
    if (row < n) v = h[row * K + k];
    if (scale) {
      v = v * scale[k] + shift[k];
      v = fmaxf(v, 0.f);
    }
    Hl[r][k] = v;
  }
  __syncthreads();
  int r = tid / C, c = tid % C;
  if (r < R) {
    int row = row0 + r;
    if (row < n) {
      float acc = 0.f;
#pragma unroll
      for (int k = 0; k < K; k++) acc = fmaf(Hl[r][k], Wl[k * C + c], acc);
      out[row * C + c] = acc;
    }
  }
}

// ---------------- aggregation + fused BN stats ----------------
// LW-lane sub-wave per node, lane = feature. Edge loop unrolled 16/4/1 with
// int4 index loads; norm factored: out = dd*(sum dinv[s]*m[s] + dd*m[d]) + b.

template <int C, int LW>
__launch_bounds__(256)
__global__ void aggregate(const float* __restrict__ m, const int* __restrict__ rowptr,
                          const int* __restrict__ csr_src, const float* __restrict__ dinv,
                          const float* __restrict__ bias, float* __restrict__ out,
                          float* __restrict__ gsum, int n) {
  constexpr int NPB = 256 / LW;
  __shared__ float ssum[256], ssq[256];
  int tid = threadIdx.x;
  int sub = tid / LW;
  int lane = tid % LW;
  int cl = (lane < C) ? lane : lane - C;  // branchless in-bounds channel
  int d = blockIdx.x * NPB + sub;
  int start = rowptr[d], end = rowptr[d + 1];
  float dd = dinv[d];
  float acc = dd * m[d * C + cl];  // self loop (gets *dd at the end)
  int j = start;
  int aligned = (start + 3) & ~3;
  int pe = aligned < end ? aligned : end;
  for (; j < pe; j++) {
    int s = csr_src[j];
    acc += dinv[s] * m[s * C + cl];
  }
  for (; j + 16 <= end; j += 16) {
    int4 s0 = *(const int4*)(csr_src + j);
    int4 s1 = *(const int4*)(csr_src + j + 4);
    int4 s2 = *(const int4*)(csr_src + j + 8);
    int4 s3 = *(const int4*)(csr_src + j + 12);
    float w0 = dinv[s0.x], w1 = dinv[s0.y], w2 = dinv[s0.z], w3 = dinv[s0.w];
    float w4 = dinv[s1.x], w5 = dinv[s1.y], w6 = dinv[s1.z], w7 = dinv[s1.w];
    float w8 = dinv[s2.x], w9 = dinv[s2.y], wa = dinv[s2.z], wb = dinv[s2.w];
    float wc = dinv[s3.x], wd = dinv[s3.y], we = dinv[s3.z], wf = dinv[s3.w];
    float v0 = m[s0.x * C + cl], v1 = m[s0.y * C + cl];
    float v2 = m[s0.z * C + cl], v3 = m[s0.w * C + cl];
    float v4 = m[s1.x * C + cl], v5 = m[s1.y * C + cl];
    float v6 = m[s1.z * C + cl], v7 = m[s1.w * C + cl];
    float v8 = m[s2.x * C + cl], v9 = m[s2.y * C + cl];
    float va = m[s2.z * C + cl], vb = m[s2.w * C + cl];
    float vc = m[s3.x * C + cl], vd = m[s3.y * C + cl];
    float ve = m[s3.z * C + cl], vf = m[s3.w * C + cl];
    acc += w0 * v0 + w1 * v1 + w2 * v2 + w3 * v3;
    acc += w4 * v4 + w5 * v5 + w6 * v6 + w7 * v7;
    acc += w8 * v8 + w9 * v9 + wa * va + wb * vb;
    acc += wc * vc + wd * vd + we * ve + wf * vf;
  }
  for (; j + 4 <= end; j += 4) {
    int4 s0 = *(const int4*)(csr_src + j);
    float w0 = dinv[s0.x], w1 = dinv[s0.y], w2 = dinv[s0.z], w3 = dinv[s0.w];
    float v0 = m[s0.x * C + cl], v1 = m[s0.y * C + cl];
    float v2 = m[s0.z * C + cl], v3 = m[s0.w * C + cl];
    acc += w0 * v0 + w1 * v1 + w2 * v2 + w3 * v3;
  }
  for (; j < end; j++) {
    int s = csr_src[j];
    acc += dinv[s] * m[s * C + cl];
  }
  float val = dd * acc;
  float s = 0.f, q = 0.f;
  if (lane < C) {
    val += bias[lane];
    out[d * C + lane] = val;
    s = val;
    q = val * val;
  }
  ssum[tid] = s;
  ssq[tid] = q;
  __syncthreads();
  if (tid < C) {
    float ts = 0.f, tq = 0.f;
#pragma unroll
    for (int k = 0; k < NPB; k++) {
      ts += ssum[k * LW + tid];
      tq += ssq[k * LW + tid];
    }
    int bucket = blockIdx.x & 31;
    atomicAdd(&gsum[bucket * 128 + tid], ts);
    atomicAdd(&gsum[bucket * 128 + 64 + tid], tq);
  }
}

// ---------------- BN finalize / apply ----------------

__global__ void bn_finalize(const float* __restrict__ gsum, const float* __restrict__ g,
                            const float* __restrict__ beta, float* __restrict__ scale,
                            float* __restrict__ shift, int C, float invn) {
  int i = threadIdx.x;
  if (i < C) {
    float s = 0.f, q = 0.f;
    for (int b = 0; b < 32; b++) {
      s += gsum[b * 128 + i];
      q += gsum[b * 128 + 64 + i];
    }
    float mean = s * invn;
    float var = q * invn - mean * mean;
    var = fmaxf(var, 0.f);
    float inv = rsqrtf(var + BN_EPS_F);
    float sc = g[i] * inv;
    scale[i] = sc;
    shift[i] = beta[i] - mean * sc;
  }
}

__global__ void bn_apply_out(const float* __restrict__ h, const float* __restrict__ scale,
                             const float* __restrict__ shift, float* __restrict__ out, int total) {
  int i = blockIdx.x * blockDim.x + threadIdx.x;
  if (i < total) {
    int c = i & 31;
    out[i] = h[i] * scale[c] + shift[c];
  }
}

// ---------------- launch ----------------

extern "C" void kernel_launch(void* const* d_in, const int* in_sizes, int n_in,
                              void* d_out, int out_size, void* d_ws, size_t ws_size,
                              hipStream_t stream) {
  const float* x = (const float*)d_in[0];
  const int* ei = (const int*)d_in[1];
  const float* W1 = (const float*)d_in[2];
  const float* b1 = (const float*)d_in[3];
  const float* g1 = (const float*)d_in[4];
  const float* be1 = (const float*)d_in[5];
  const float* W2 = (const float*)d_in[6];
  const float* b2 = (const float*)d_in[7];
  const float* g2 = (const float*)d_in[8];
  const float* be2 = (const float*)d_in[9];
  const float* W3 = (const float*)d_in[10];
  const float* b3 = (const float*)d_in[11];
  const float* g3 = (const float*)d_in[12];
  const float* be3 = (const float*)d_in[13];
  float* out = (float*)d_out;

  const int* src = ei;
  const int* dst = ei + NE;

  char* ws = (char*)d_ws;
  size_t off = 0;
  auto alloc = [&](size_t bytes) -> void* {
    void* p = ws + off;
    off += bytes;
    off = (off + 255) & ~(size_t)255;
    return p;
  };
  int* deg = (int*)alloc(NN * 4);
  int* rowptr = (int*)alloc((NN + 1) * 4);
  int* cursor = (int*)alloc(NN * 4);
  int* bsums = (int*)alloc(128 * 4);
  int* csr_src = (int*)alloc(NE * 4);
  float* dinv = (float*)alloc(NN * 4);
  float* gsum = (float*)alloc(3 * 32 * 128 * 4);  // per layer: 32 buckets x [sum64|sq64]
  float* scsh = (float*)alloc(3 * 128 * 4);       // per layer: [scale64|shift64]
  float* bufA = (float*)alloc((size_t)NN * 64 * 4);
  float* bufB = (float*)alloc((size_t)NN * 64 * 4);

  hipMemsetAsync(deg, 0, NN * 4, stream);
  hipMemsetAsync(gsum, 0, 3 * 32 * 128 * 4, stream);

  const int nb = (NN + 1023) / 1024;  // 98
  count_deg<<<(NE + 255) / 256, 256, 0, stream>>>(dst, deg, NE);
  scan_block_sums<<<nb, 256, 0, stream>>>(deg, bsums, NN);
  scan_bsums<<<1, 128, 0, stream>>>(bsums, nb, rowptr, NN);
  scan_write_rowptr<<<nb, 256, 0, stream>>>(deg, bsums, rowptr, cursor, dinv, NN);
  {
    int gb = (NE / 4 + 255) / 256;  // 1563 blocks per range
    fill_csr_ranged<<<gb * NRANGE, 256, 0, stream>>>(src, dst, cursor, csr_src, NE);
  }

  const float invn = 1.f / (float)NN;

  // layer 1: x[.,20] @ W1 -> 64
  gemm_affine<20, 64, 4><<<(NN + 3) / 4, 256, 0, stream>>>(x, W1, nullptr, nullptr, bufA, NN);
  aggregate<64, 64><<<NN / 4, 256, 0, stream>>>(bufA, rowptr, csr_src, dinv, b1, bufB, gsum, NN);
  bn_finalize<<<1, 64, 0, stream>>>(gsum, g1, be1, scsh + 0, scsh + 64, 64, invn);

  // layer 2: relu(bn(h)) @ W2 -> 48
  gemm_affine<64, 48, 5><<<(NN + 4) / 5, 256, 0, stream>>>(bufB, W2, scsh + 0, scsh + 64, bufA, NN);
  aggregate<48, 64><<<NN / 4, 256, 0, stream>>>(bufA, rowptr, csr_src, dinv, b2, bufB, gsum + 4096, NN);
  bn_finalize<<<1, 64, 0, stream>>>(gsum + 4096, g2, be2, scsh + 128, scsh + 192, 48, invn);

  // layer 3: relu(bn(h)) @ W3 -> 32
  gemm_affine<48, 32, 8><<<(NN + 7) / 8, 256, 0, stream>>>(bufB, W3, scsh + 128, scsh + 192, bufA, NN);
  aggregate<32, 32><<<NN / 8, 256, 0, stream>>>(bufA, rowptr, csr_src, dinv, b3, bufB, gsum + 8192, NN);
  bn_finalize<<<1, 64, 0, stream>>>(gsum + 8192, g3, be3, scsh + 256, scsh + 320, 32, invn);

  bn_apply_out<<<(NN * 32 + 255) / 256, 256, 0, stream>>>(bufB, scsh + 256, scsh + 320, out, NN * 32);
}

// Round 5
// 458.705 us; speedup vs baseline: 1.4583x; 1.3236x over previous
//
#include <hip/hip_runtime.h>

// GCN 3-layer: N=100000 nodes, E=1600000 edges, dims 20->64->48->32.
// CSR-by-dst (counting sort, XCD-ranged scatter). Gathered feature streams are
// stored bf16x2 pre-scaled by dinv[row] so the edge loop is a pure sum of
// unpacked bf16 pairs. Layer 1 is aggregate-first (aggregate 20-ch x, then
// GEMM with fused BN stats); layers 2/3 are GEMM-first (gather the smaller
// post-GEMM features). All accumulation fp32; all row strides 64B multiples.

#define NN 100000
#define NE 1600000
constexpr float BN_EPS_F = 1e-5f;
#define NRANGE 8
#define RANGE_SZ ((NN + NRANGE - 1) / NRANGE)  // 12500

// ---------------- bf16 helpers (RTE) ----------------

__device__ __forceinline__ unsigned f2bf(float f) {
  union { float f; unsigned u; } v; v.f = f;
  return (v.u + 0x7fffu + ((v.u >> 16) & 1u)) >> 16;
}
__device__ __forceinline__ unsigned pack_bf2(float f0, float f1) {
  return f2bf(f0) | (f2bf(f1) << 16);
}
__device__ __forceinline__ float bf_lo(unsigned u) {
  union { unsigned u; float f; } v; v.u = u << 16; return v.f;
}
__device__ __forceinline__ float bf_hi(unsigned u) {
  union { unsigned u; float f; } v; v.u = u & 0xffff0000u; return v.f;
}

// ---------------- CSR build ----------------

__global__ void count_deg(const int* __restrict__ dst, int* __restrict__ deg, int e) {
  int i = blockIdx.x * blockDim.x + threadIdx.x;
  if (i < e) atomicAdd(&deg[dst[i]], 1);
}

__global__ void scan_block_sums(const int* __restrict__ deg, int* __restrict__ bsums, int n) {
  __shared__ int sd[256];
  int tid = threadIdx.x;
  int base = blockIdx.x * 1024;
  int s = 0;
#pragma unroll
  for (int j = 0; j < 4; j++) {
    int idx = base + tid * 4 + j;
    if (idx < n) s += deg[idx];
  }
  sd[tid] = s;
  __syncthreads();
  for (int o = 128; o > 0; o >>= 1) {
    if (tid < o) sd[tid] += sd[tid + o];
    __syncthreads();
  }
  if (tid == 0) bsums[blockIdx.x] = sd[0];
}

__global__ void scan_bsums(int* __restrict__ bsums, int nb, int* __restrict__ rowptr, int n) {
  __shared__ int sd[128];
  int tid = threadIdx.x;
  int v = (tid < nb) ? bsums[tid] : 0;
  sd[tid] = v;
  __syncthreads();
  for (int o = 1; o < 128; o <<= 1) {
    int t = (tid >= o) ? sd[tid - o] : 0;
    __syncthreads();
    sd[tid] += t;
    __syncthreads();
  }
  if (tid < nb) bsums[tid] = sd[tid] - v;  // exclusive
  if (tid == nb - 1) rowptr[n] = sd[tid];  // grand total
}

// also computes dinv = rsqrt(deg+1) (self loop) — fused
__global__ void scan_write_rowptr(const int* __restrict__ deg, const int* __restrict__ bsums,
                                  int* __restrict__ rowptr, int* __restrict__ cursor,
                                  float* __restrict__ dinv, int n) {
  __shared__ int sd[256];
  int tid = threadIdx.x;
  int base = blockIdx.x * 1024;
  int c[4];
  int s = 0;
#pragma unroll
  for (int j = 0; j < 4; j++) {
    int idx = base + tid * 4 + j;
    c[j] = (idx < n) ? deg[idx] : 0;
    s += c[j];
  }
  sd[tid] = s;
  __syncthreads();
  for (int o = 1; o < 256; o <<= 1) {
    int t = (tid >= o) ? sd[tid - o] : 0;
    __syncthreads();
    sd[tid] += t;
    __syncthreads();
  }
  int off = bsums[blockIdx.x] + sd[tid] - s;
#pragma unroll
  for (int j = 0; j < 4; j++) {
    int idx = base + tid * 4 + j;
    if (idx < n) {
      rowptr[idx] = off;
      cursor[idx] = off;
      dinv[idx] = rsqrtf((float)(c[j] + 1));
      off += c[j];
    }
  }
}

// XCD-range-partitioned scatter: block handles dst-range blockIdx%8 only so
// cursor/csr slices stay hot in one XCD's L2 (locality heuristic only).
__global__ void fill_csr_ranged(const int* __restrict__ src, const int* __restrict__ dst,
                                int* __restrict__ cursor, int* __restrict__ csr_src, int e) {
  int rng = blockIdx.x & (NRANGE - 1);
  int gb = blockIdx.x >> 3;
  int lo = rng * RANGE_SZ;
  int hi = lo + RANGE_SZ;
  int i0 = (gb * 256 + threadIdx.x) * 4;
  if (i0 >= e) return;  // e % 4 == 0
  int4 s = *(const int4*)(src + i0);
  int4 d = *(const int4*)(dst + i0);
  if (d.x >= lo && d.x < hi) { int p = atomicAdd(&cursor[d.x], 1); csr_src[p] = s.x; }
  if (d.y >= lo && d.y < hi) { int p = atomicAdd(&cursor[d.y], 1); csr_src[p] = s.y; }
  if (d.z >= lo && d.z < hi) { int p = atomicAdd(&cursor[d.z], 1); csr_src[p] = s.z; }
  if (d.w >= lo && d.w < hi) { int p = atomicAdd(&cursor[d.w], 1); csr_src[p] = s.w; }
}

// ---------------- x -> bf16x2, pre-scaled by dinv[row], stride 16 uints ----------------

__global__ void convert_x(const float* __restrict__ x, const float* __restrict__ dinv,
                          unsigned* __restrict__ xb) {
  int t = blockIdx.x * 256 + threadIdx.x;
  if (t >= NN * 16) return;
  int row = t >> 4, i = t & 15;
  unsigned u = 0;
  if (i < 10) {
    float dd = dinv[row];
    float2 f = *(const float2*)(x + row * 20 + 2 * i);
    u = pack_bf2(dd * f.x, dd * f.y);
  }
  xb[t] = u;
}

// ---------------- aggregation of pre-scaled bf16x2 rows ----------------
// LW-lane sub-wave per node, lane holds channels (2*lane, 2*lane+1).
// out[d] = dinv[d] * (sum_e m'[src] + m'[d]) + bias,  m' = dinv[row]*m.
// NU real uints per row (stride S2); lanes >= NU duplicate (loads in-bounds)
// and write zero pad. Optional fused BN stats via bucketed atomics.

template <int NU, int S2, int LW, bool STATS>
__launch_bounds__(256)
__global__ void aggregate_bf(const unsigned* __restrict__ mb, const int* __restrict__ rowptr,
                             const int* __restrict__ csr_src, const float* __restrict__ dinv,
                             const float* __restrict__ bias, float* __restrict__ out,
                             float* __restrict__ gsum) {
  constexpr int NPB = 256 / LW;
  constexpr int OS = 2 * LW;  // out row stride (floats)
  __shared__ float2 ssum[256], ssq[256];
  int tid = threadIdx.x;
  int sub = tid / LW, lane = tid % LW;
  int cl = (lane < NU) ? lane : lane - NU;
  int d = blockIdx.x * NPB + sub;
  int start = rowptr[d], end = rowptr[d + 1];
  unsigned su = mb[(size_t)d * S2 + cl];  // self loop: m'[d]
  float acc0 = bf_lo(su), acc1 = bf_hi(su);
  int j = start;
  int aligned = (start + 3) & ~3;
  int pe = aligned < end ? aligned : end;
  for (; j < pe; j++) {
    unsigned u = mb[(size_t)csr_src[j] * S2 + cl];
    acc0 += bf_lo(u); acc1 += bf_hi(u);
  }
  for (; j + 16 <= end; j += 16) {
    int4 s0 = *(const int4*)(csr_src + j);
    int4 s1 = *(const int4*)(csr_src + j + 4);
    int4 s2 = *(const int4*)(csr_src + j + 8);
    int4 s3 = *(const int4*)(csr_src + j + 12);
    unsigned u0 = mb[(size_t)s0.x * S2 + cl], u1 = mb[(size_t)s0.y * S2 + cl];
    unsigned u2 = mb[(size_t)s0.z * S2 + cl], u3 = mb[(size_t)s0.w * S2 + cl];
    unsigned u4 = mb[(size_t)s1.x * S2 + cl], u5 = mb[(size_t)s1.y * S2 + cl];
    unsigned u6 = mb[(size_t)s1.z * S2 + cl], u7 = mb[(size_t)s1.w * S2 + cl];
    unsigned u8 = mb[(size_t)s2.x * S2 + cl], u9 = mb[(size_t)s2.y * S2 + cl];
    unsigned ua = mb[(size_t)s2.z * S2 + cl], ub = mb[(size_t)s2.w * S2 + cl];
    unsigned uc = mb[(size_t)s3.x * S2 + cl], ud = mb[(size_t)s3.y * S2 + cl];
    unsigned ue = mb[(size_t)s3.z * S2 + cl], uf = mb[(size_t)s3.w * S2 + cl];
    acc0 += bf_lo(u0) + bf_lo(u1) + bf_lo(u2) + bf_lo(u3);
    acc1 += bf_hi(u0) + bf_hi(u1) + bf_hi(u2) + bf_hi(u3);
    acc0 += bf_lo(u4) + bf_lo(u5) + bf_lo(u6) + bf_lo(u7);
    acc1 += bf_hi(u4) + bf_hi(u5) + bf_hi(u6) + bf_hi(u7);
    acc0 += bf_lo(u8) + bf_lo(u9) + bf_lo(ua) + bf_lo(ub);
    acc1 += bf_hi(u8) + bf_hi(u9) + bf_hi(ua) + bf_hi(ub);
    acc0 += bf_lo(uc) + bf_lo(ud) + bf_lo(ue) + bf_lo(uf);
    acc1 += bf_hi(uc) + bf_hi(ud) + bf_hi(ue) + bf_hi(uf);
  }
  for (; j + 4 <= end; j += 4) {
    int4 s0 = *(const int4*)(csr_src + j);
    unsigned u0 = mb[(size_t)s0.x * S2 + cl], u1 = mb[(size_t)s0.y * S2 + cl];
    unsigned u2 = mb[(size_t)s0.z * S2 + cl], u3 = mb[(size_t)s0.w * S2 + cl];
    acc0 += bf_lo(u0) + bf_lo(u1) + bf_lo(u2) + bf_lo(u3);
    acc1 += bf_hi(u0) + bf_hi(u1) + bf_hi(u2) + bf_hi(u3);
  }
  for (; j < end; j++) {
    unsigned u = mb[(size_t)csr_src[j] * S2 + cl];
    acc0 += bf_lo(u); acc1 += bf_hi(u);
  }
  float dd = dinv[d];
  float v0 = dd * acc0, v1 = dd * acc1;
  if (bias) { v0 += bias[2 * cl]; v1 += bias[2 * cl + 1]; }
  if (lane >= NU) { v0 = 0.f; v1 = 0.f; }  // zero pad (keeps lines full)
  *(float2*)(out + (size_t)d * OS + 2 * lane) = make_float2(v0, v1);
  if (STATS) {
    ssum[tid] = make_float2(v0, v1);
    ssq[tid] = make_float2(v0 * v0, v1 * v1);
    __syncthreads();
    if (tid < LW) {
      float s0 = 0.f, s1 = 0.f, q0 = 0.f, q1 = 0.f;
#pragma unroll
      for (int k = 0; k < NPB; k++) {
        float2 a = ssum[k * LW + tid];
        float2 b = ssq[k * LW + tid];
        s0 += a.x; s1 += a.y; q0 += b.x; q1 += b.y;
      }
      if (tid < NU) {
        float* gs = gsum + (blockIdx.x & 31) * 128;
        atomicAdd(&gs[2 * tid], s0);
        atomicAdd(&gs[2 * tid + 1], s1);
        atomicAdd(&gs[64 + 2 * tid], q0);
        atomicAdd(&gs[64 + 2 * tid + 1], q1);
      }
    }
  }
}

// ---------------- layer-1 GEMM: agg_x[.,20] @ W1 + b1 -> h1[.,64] fp32, fused BN stats ----------------

__launch_bounds__(256)
__global__ void gemm1_stats(const float* __restrict__ h, const float* __restrict__ W,
                            const float* __restrict__ bias, float* __restrict__ out,
                            float* __restrict__ gsum) {
  __shared__ float Wl[20 * 64];
  __shared__ float Hl[8][32];
  __shared__ float2 ssum[256], ssq[256];
  int tid = threadIdx.x;
  int row0 = blockIdx.x * 8;
  for (int i = tid; i < 20 * 64; i += 256) Wl[i] = W[i];
  {
    int r = tid >> 5, k = tid & 31;
    Hl[r][k] = h[(size_t)(row0 + r) * 32 + k];
  }
  __syncthreads();
  int r = tid >> 5, c2 = tid & 31;
  float acc0 = bias[2 * c2], acc1 = bias[2 * c2 + 1];
#pragma unroll
  for (int k = 0; k < 20; k++) {
    float a = Hl[r][k];
    acc0 = fmaf(a, Wl[k * 64 + 2 * c2], acc0);
    acc1 = fmaf(a, Wl[k * 64 + 2 * c2 + 1], acc1);
  }
  *(float2*)(out + (size_t)(row0 + r) * 64 + 2 * c2) = make_float2(acc0, acc1);
  ssum[tid] = make_float2(acc0, acc1);
  ssq[tid] = make_float2(acc0 * acc0, acc1 * acc1);
  __syncthreads();
  if (tid < 32) {
    float s0 = 0.f, s1 = 0.f, q0 = 0.f, q1 = 0.f;
#pragma unroll
    for (int k = 0; k < 8; k++) {
      float2 a = ssum[k * 32 + tid];
      float2 b = ssq[k * 32 + tid];
      s0 += a.x; s1 += a.y; q0 += b.x; q1 += b.y;
    }
    float* gs = gsum + (blockIdx.x & 31) * 128;
    atomicAdd(&gs[2 * tid], s0);
    atomicAdd(&gs[2 * tid + 1], s1);
    atomicAdd(&gs[64 + 2 * tid], q0);
    atomicAdd(&gs[64 + 2 * tid + 1], q1);
  }
}

// ---------------- GEMM with affine+relu input, bf16x2 pre-scaled output ----------------
// h: [n,HS] fp32; out: [n,S2] uints (channels 2*c2,2*c2+1); S2*R == 256.

template <int K, int HS, int C, int S2, int R>
__launch_bounds__(256)
__global__ void gemm_bf(const float* __restrict__ h, const float* __restrict__ W,
                        const float* __restrict__ scale, const float* __restrict__ shift,
                        const float* __restrict__ dinv, unsigned* __restrict__ out) {
  __shared__ float Wl[K * C];
  __shared__ float Hl[R][K];
  int tid = threadIdx.x;
  int row0 = blockIdx.x * R;
  for (int i = tid; i < K * C; i += 256) Wl[i] = W[i];
  for (int i = tid; i < R * K; i += 256) {
    int r = i / K, k = i % K;
    float v = h[(size_t)(row0 + r) * HS + k];
    v = fmaf(v, scale[k], shift[k]);
    Hl[r][k] = fmaxf(v, 0.f);
  }
  __syncthreads();
  int r = tid / S2, c2 = tid % S2;
  unsigned u = 0;
  if (2 * c2 < C) {
    float acc0 = 0.f, acc1 = 0.f;
#pragma unroll
    for (int k = 0; k < K; k++) {
      float a = Hl[r][k];
      acc0 = fmaf(a, Wl[k * C + 2 * c2], acc0);
      acc1 = fmaf(a, Wl[k * C + 2 * c2 + 1], acc1);
    }
    float dd = dinv[row0 + r];
    u = pack_bf2(dd * acc0, dd * acc1);
  }
  out[(size_t)(row0 + r) * S2 + c2] = u;
}

// ---------------- BN finalize / apply ----------------

__global__ void bn_finalize(const float* __restrict__ gsum, const float* __restrict__ g,
                            const float* __restrict__ beta, float* __restrict__ scale,
                            float* __restrict__ shift, int C, float invn) {
  int i = threadIdx.x;
  if (i < C) {
    float s = 0.f, q = 0.f;
    for (int b = 0; b < 32; b++) {
      s += gsum[b * 128 + i];
      q += gsum[b * 128 + 64 + i];
    }
    float mean = s * invn;
    float var = q * invn - mean * mean;
    var = fmaxf(var, 0.f);
    float inv = rsqrtf(var + BN_EPS_F);
    float sc = g[i] * inv;
    scale[i] = sc;
    shift[i] = beta[i] - mean * sc;
  }
}

__global__ void bn_apply_out(const float* __restrict__ h, const float* __restrict__ scale,
                             const float* __restrict__ shift, float* __restrict__ out, int total) {
  int i = blockIdx.x * blockDim.x + threadIdx.x;
  if (i < total) {
    int c = i & 31;
    out[i] = h[i] * scale[c] + shift[c];
  }
}

// ---------------- launch ----------------

extern "C" void kernel_launch(void* const* d_in, const int* in_sizes, int n_in,
                              void* d_out, int out_size, void* d_ws, size_t ws_size,
                              hipStream_t stream) {
  const float* x = (const float*)d_in[0];
  const int* ei = (const int*)d_in[1];
  const float* W1 = (const float*)d_in[2];
  const float* b1 = (const float*)d_in[3];
  const float* g1 = (const float*)d_in[4];
  const float* be1 = (const float*)d_in[5];
  const float* W2 = (const float*)d_in[6];
  const float* b2 = (const float*)d_in[7];
  const float* g2 = (const float*)d_in[8];
  const float* be2 = (const float*)d_in[9];
  const float* W3 = (const float*)d_in[10];
  const float* b3 = (const float*)d_in[11];
  const float* g3 = (const float*)d_in[12];
  const float* be3 = (const float*)d_in[13];
  float* out = (float*)d_out;

  const int* src = ei;
  const int* dst = ei + NE;

  char* ws = (char*)d_ws;
  size_t off = 0;
  auto alloc = [&](size_t bytes) -> void* {
    void* p = ws + off;
    off += bytes;
    off = (off + 255) & ~(size_t)255;
    return p;
  };
  int* deg = (int*)alloc(NN * 4);
  int* rowptr = (int*)alloc((NN + 1) * 4);
  int* cursor = (int*)alloc(NN * 4);
  int* bsums = (int*)alloc(128 * 4);
  int* csr_src = (int*)alloc(NE * 4);
  float* dinv = (float*)alloc(NN * 4);
  float* gsum = (float*)alloc(3 * 32 * 128 * 4);  // per layer: 32 buckets x [sum64|sq64]
  float* scsh = (float*)alloc(3 * 128 * 4);       // per layer: [scale64|shift64]
  float* bufP = (float*)alloc((size_t)NN * 32 * 4);  // agg_x / m2b / m3b
  float* bufQ = (float*)alloc((size_t)NN * 64 * 4);  // h1 / h2
  float* bufR = (float*)alloc((size_t)NN * 32 * 4);  // xb / h3

  unsigned* xb = (unsigned*)bufR;     // N x 16 uints
  float* aggx = bufP;                 // N x 32 fp32
  float* h1 = bufQ;                   // N x 64 fp32
  unsigned* m2b = (unsigned*)bufP;    // N x 32 uints (24 real)
  float* h2 = bufQ;                   // N x 64 fp32 (48 real)
  unsigned* m3b = (unsigned*)bufP;    // N x 16 uints
  float* h3 = bufR;                   // N x 32 fp32

  hipMemsetAsync(deg, 0, NN * 4, stream);
  hipMemsetAsync(gsum, 0, 3 * 32 * 128 * 4, stream);

  const int nb = (NN + 1023) / 1024;  // 98
  count_deg<<<(NE + 255) / 256, 256, 0, stream>>>(dst, deg, NE);
  scan_block_sums<<<nb, 256, 0, stream>>>(deg, bsums, NN);
  scan_bsums<<<1, 128, 0, stream>>>(bsums, nb, rowptr, NN);
  scan_write_rowptr<<<nb, 256, 0, stream>>>(deg, bsums, rowptr, cursor, dinv, NN);
  {
    int gb = (NE / 4 + 255) / 256;  // 1563 blocks per range
    fill_csr_ranged<<<gb * NRANGE, 256, 0, stream>>>(src, dst, cursor, csr_src, NE);
  }
  convert_x<<<NN * 16 / 256, 256, 0, stream>>>(x, dinv, xb);

  const float invn = 1.f / (float)NN;

  // layer 1 (aggregate-first): agg_x = A_hat x ; h1 = agg_x @ W1 + b1 (stats fused)
  aggregate_bf<10, 16, 16, false><<<NN / 16, 256, 0, stream>>>(xb, rowptr, csr_src, dinv,
                                                               nullptr, aggx, nullptr);
  gemm1_stats<<<NN / 8, 256, 0, stream>>>(aggx, W1, b1, h1, gsum);
  bn_finalize<<<1, 64, 0, stream>>>(gsum, g1, be1, scsh + 0, scsh + 64, 64, invn);

  // layer 2 (gemm-first): m2' = dinv .* (relu(bn1(h1)) @ W2) ; h2 = A_hat-sum + b2 (stats fused)
  gemm_bf<64, 64, 48, 32, 8><<<NN / 8, 256, 0, stream>>>(h1, W2, scsh + 0, scsh + 64, dinv, m2b);
  aggregate_bf<24, 32, 32, true><<<NN / 8, 256, 0, stream>>>(m2b, rowptr, csr_src, dinv, b2, h2,
                                                             gsum + 4096);
  bn_finalize<<<1, 64, 0, stream>>>(gsum + 4096, g2, be2, scsh + 128, scsh + 192, 48, invn);

  // layer 3 (gemm-first): m3' = dinv .* (relu(bn2(h2)) @ W3) ; h3 = A_hat-sum + b3 (stats fused)
  gemm_bf<48, 64, 32, 16, 16><<<NN / 16, 256, 0, stream>>>(h2, W3, scsh + 128, scsh + 192, dinv, m3b);
  aggregate_bf<16, 16, 16, true><<<NN / 16, 256, 0, stream>>>(m3b, rowptr, csr_src, dinv, b3, h3,
                                                              gsum + 8192);
  bn_finalize<<<1, 64, 0, stream>>>(gsum + 8192, g3, be3, scsh + 256, scsh + 320, 32, invn);

  bn_apply_out<<<(NN * 32 + 255) / 256, 256, 0, stream>>>(h3, scsh + 256, scsh + 320, out, NN * 32);
}